// Round 4
// baseline (1884.212 us; speedup 1.0000x reference)
//
#include <hip/hip_runtime.h>
#include <hip/hip_fp16.h>
#include <math.h>
#include <stdint.h>

// Problem constants
#define NB   64      // batch
#define NS   128     // seq len
#define NW   16      // word length (chars)
#define CD   50      // char emb dim
#define NF_  50      // filters per kernel size
#define WD   300     // word emb dim
#define COMB 450     // WD + 3*NF  (even -> 225 f16 pairs)
#define HID  256
#define G4   1024    // 4*HID
#define NLAB 5

typedef _Float16 h2_t __attribute__((ext_vector_type(2)));

__device__ __forceinline__ float sigf(float x)   { return 1.0f / (1.0f + __expf(-x)); }
__device__ __forceinline__ float tanhf_(float x) { return 1.0f - 2.0f / (__expf(2.0f * x) + 1.0f); }

__device__ __forceinline__ float dot2f(uint32_t a, uint32_t b, float c) {
#if __has_builtin(__builtin_amdgcn_fdot2)
    return __builtin_amdgcn_fdot2(__builtin_bit_cast(h2_t, a),
                                  __builtin_bit_cast(h2_t, b), c, false);
#else
    h2_t ah = __builtin_bit_cast(h2_t, a), bh = __builtin_bit_cast(h2_t, b);
    return c + (float)ah[0] * (float)bh[0] + (float)ah[1] * (float)bh[1];
#endif
}

__device__ __forceinline__ uint32_t packh2(float lo, float hi) {
    __half l = __float2half(lo), h = __float2half(hi);
    return ((uint32_t)__half_as_ushort(h) << 16) | (uint32_t)__half_as_ushort(l);
}

// ---------------- CNN + embedding concat -> x0p (8192 x 225 u32, f16 pairs) --
__global__ __launch_bounds__(256) void cnn_embed(
    const int* __restrict__ word_ids, const int* __restrict__ char_ids,
    const float* __restrict__ word_emb, const float* __restrict__ char_emb,
    const float* __restrict__ w3, const float* __restrict__ b3,
    const float* __restrict__ w4, const float* __restrict__ b4,
    const float* __restrict__ w5, const float* __restrict__ b5,
    uint32_t* __restrict__ x0p)
{
    __shared__ float ce[4][NW][CD];
    __shared__ float cv[4][152];            // conv outputs per position
    int tid  = threadIdx.x;
    int g    = tid >> 6;
    int lane = tid & 63;
    int pos  = blockIdx.x * 4 + g;          // 0..8191

    const int* cid = char_ids + (size_t)pos * NW;
    for (int idx = lane; idx < NW * CD; idx += 64) {
        int w  = idx / CD;
        int cc = idx - w * CD;
        ce[g][w][cc] = char_emb[(size_t)cid[w] * CD + cc];
    }
    // word embedding -> packed pairs 0..149
    {
        int wid = word_ids[pos];
        const float* src = word_emb + (size_t)wid * WD;
        uint32_t* dst = x0p + (size_t)pos * 225;
        for (int idx = lane; idx < 150; idx += 64) {
            float2 v = *(const float2*)(src + 2 * idx);
            dst[idx] = packh2(v.x, v.y);
        }
    }
    __syncthreads();

    int f = lane;
    if (f < NF_) {
        float a3[16], a4[17], a5[16];
        float bb3 = b3[f], bb4 = b4[f], bb5 = b5[f];
#pragma unroll
        for (int p = 0; p < 16; ++p) { a3[p] = bb3; a5[p] = bb5; }
#pragma unroll
        for (int p = 0; p < 17; ++p) a4[p] = bb4;

        for (int c = 0; c < CD; ++c) {
            float w3r[3], w4r[4], w5r[5];
#pragma unroll
            for (int t = 0; t < 3; ++t) w3r[t] = w3[(t * CD + c) * NF_ + f];
#pragma unroll
            for (int t = 0; t < 4; ++t) w4r[t] = w4[(t * CD + c) * NF_ + f];
#pragma unroll
            for (int t = 0; t < 5; ++t) w5r[t] = w5[(t * CD + c) * NF_ + f];
#pragma unroll
            for (int ip = 0; ip < 16; ++ip) {
                float v = ce[g][ip][c];
#pragma unroll
                for (int t = 0; t < 3; ++t) { int p = ip + 1 - t; if (p >= 0 && p < 16) a3[p] += v * w3r[t]; }
#pragma unroll
                for (int t = 0; t < 4; ++t) { int p = ip + 2 - t; if (p >= 0 && p < 17) a4[p] += v * w4r[t]; }
#pragma unroll
                for (int t = 0; t < 5; ++t) { int p = ip + 2 - t; if (p >= 0 && p < 16) a5[p] += v * w5r[t]; }
            }
        }
        float m3 = 0.f, m4 = 0.f, m5 = 0.f;
#pragma unroll
        for (int p = 0; p < 16; ++p) m3 = fmaxf(m3, a3[p]);
#pragma unroll
        for (int p = 0; p < 17; ++p) m4 = fmaxf(m4, a4[p]);
#pragma unroll
        for (int p = 0; p < 16; ++p) m5 = fmaxf(m5, a5[p]);
        cv[g][f] = m3; cv[g][50 + f] = m4; cv[g][100 + f] = m5;
    }
    __syncthreads();
    // pack conv pairs 150..224
    {
        uint32_t* dst = x0p + (size_t)pos * 225 + 150;
        for (int idx = lane; idx < 75; idx += 64)
            dst[idx] = packh2(cv[g][2 * idx], cv[g][2 * idx + 1]);
    }
}

// ------------- weight packs ---------------------------------------------------
// Wih: P[kp*1024 + n] = h2(W[2kp][n], W[2kp+1][n])
__global__ __launch_bounds__(256) void pack_wih(
    const float* __restrict__ W, int K, uint32_t* __restrict__ P)
{
    int idx = blockIdx.x * 256 + threadIdx.x;
    int K2 = K >> 1;
    if (idx >= K2 * 1024) return;
    int n = idx & 1023, kp = idx >> 10;
    int k0 = 2 * kp;
    float lo = W[(size_t)k0 * 1024 + n];
    float hi = W[(size_t)(k0 + 1) * 1024 + n];
    P[idx] = packh2(lo, hi);
}

// Whh: P[(kq*1024+col)*4+kk] = h2(W[8kq+2kk][col], W[8kq+2kk+1][col])
__global__ __launch_bounds__(256) void pack_whh(
    const float* __restrict__ W, uint32_t* __restrict__ P)
{
    int idx = blockIdx.x * 256 + threadIdx.x;     // 32*1024*4 = 131072
    if (idx >= 131072) return;
    int kk = idx & 3, col = (idx >> 2) & 1023, kq = idx >> 12;
    int k = kq * 8 + kk * 2;
    float lo = W[(size_t)k * G4 + col];
    float hi = W[(size_t)(k + 1) * G4 + col];
    P[idx] = packh2(lo, hi);
}

// ------------- xg GEMM (f16 dot2): C[8192 x 1024] = Ap @ Wp + bias -----------
__global__ __launch_bounds__(256) void gemm_f16(
    const uint32_t* __restrict__ Ap, int K2,
    const uint32_t* __restrict__ Wpf, const uint32_t* __restrict__ Wpr,
    const float* __restrict__ bf, const float* __restrict__ br,
    float* __restrict__ Cf, float* __restrict__ Cr)
{
    int by  = blockIdx.y;
    int dir = by >> 3;
    int n0  = (by & 7) * 128;
    int m0  = blockIdx.x * 128;
    const uint32_t* Wp = dir ? Wpr : Wpf;
    const float* bias  = dir ? br : bf;
    float* C           = dir ? Cr : Cf;

    __shared__ uint32_t As[8][132];
    __shared__ uint32_t Bs[8][132];

    int tid = threadIdx.x;
    int ka = tid & 7,  ma = tid >> 3;       // A: 8 kp x 32 rows (x4)
    int kb = tid >> 7, nb = tid & 127;      // B: 2 kp (x4) x 128 n
    int tx = tid & 15, ty = tid >> 4;
    int row0 = ty * 8, col0 = tx * 8;

    float acc[8][8] = {};

    for (int kp0 = 0; kp0 < K2; kp0 += 8) {
#pragma unroll
        for (int i = 0; i < 4; ++i) {
            uint32_t v = 0;
            if (kp0 + ka < K2) v = Ap[(size_t)(m0 + ma + 32 * i) * K2 + kp0 + ka];
            As[ka][ma + 32 * i] = v;
        }
#pragma unroll
        for (int i = 0; i < 4; ++i) {
            int kp = kb + 2 * i;
            uint32_t v = 0;
            if (kp0 + kp < K2) v = Wp[(size_t)(kp0 + kp) * G4 + n0 + nb];
            Bs[kp][nb] = v;
        }
        __syncthreads();
#pragma unroll
        for (int kp = 0; kp < 8; ++kp) {
            uint32_t a[8], b[8];
            *(uint4*)&a[0] = *(const uint4*)&As[kp][row0];
            *(uint4*)&a[4] = *(const uint4*)&As[kp][row0 + 4];
            *(uint4*)&b[0] = *(const uint4*)&Bs[kp][col0];
            *(uint4*)&b[4] = *(const uint4*)&Bs[kp][col0 + 4];
#pragma unroll
            for (int i = 0; i < 8; ++i)
#pragma unroll
                for (int j = 0; j < 8; ++j)
                    acc[i][j] = dot2f(a[i], b[j], acc[i][j]);
        }
        __syncthreads();
    }
#pragma unroll
    for (int i = 0; i < 8; ++i) {
        size_t crow = (size_t)(m0 + row0 + i) * G4 + n0 + col0;
#pragma unroll
        for (int j = 0; j < 8; j += 4) {
            float4 o;
            o.x = acc[i][j]     + bias[n0 + col0 + j];
            o.y = acc[i][j + 1] + bias[n0 + col0 + j + 1];
            o.z = acc[i][j + 2] + bias[n0 + col0 + j + 2];
            o.w = acc[i][j + 3] + bias[n0 + col0 + j + 3];
            *(float4*)&C[crow + j] = o;
        }
    }
}

// ------------- LSTM recurrence v4: 64 blocks x 1024 thr, pipelined dot2 ------
// Block per (batch-pair, dir). Thread t owns gate-column t for BOTH batch rows.
// Per k-octet: 1 dwordx4 weight load (depth-2 pipelined) + 2 broadcast
// ds_read_b128 (h) + 8 v_dot2_f32_f16. xg added after dot loop (latency hidden).
__global__ __launch_bounds__(1024) void lstm_rec4(
    const float* __restrict__ xg_f, const float* __restrict__ xg_r,
    const uint32_t* __restrict__ Pf, const uint32_t* __restrict__ Pr,
    uint32_t* __restrict__ outp)   // [8192][256] u32: row*256 + d*128 + jp
{
    int bid = blockIdx.x;           // 64 = 32 batch-pairs x 2 dirs
    int bp = bid >> 1, d = bid & 1;
    int b0 = 2 * bp;
    const float* xg = d ? xg_r : xg_f;
    const uint32_t* P = d ? Pr : Pf;   // [32][1024][4] u32

    __shared__ alignas(16) uint32_t hp[2][128];   // h packed f16 pairs
    __shared__ float gates[2][G4];

    int t = threadIdx.x;            // col 0..1023

    if (t < 256) hp[t >> 7][t & 127] = 0;
    float cst = 0.f;                // cell state for (bb=t>>8, j=t&255), t<512
    __syncthreads();

    const uint32_t* pwbase = P + 4 * (size_t)t;

    for (int s = 0; s < NS; ++s) {
        int te = d ? (NS - 1 - s) : s;
        size_t r0 = ((size_t)b0 * NS + te) * G4 + t;
        size_t r1 = r0 + (size_t)NS * G4;
        float xa = xg[r0];          // issued early; first use after dot loop
        float xb = xg[r1];

        float a0 = 0.f, a1 = 0.f;
        const uint32_t* pw = pwbase;
        uint4 w0 = *(const uint4*)(pw);
        uint4 w1 = *(const uint4*)(pw + 4096);
#pragma unroll 4
        for (int kq = 0; kq < 32; ++kq) {
            uint4 wc = w0;
            w0 = w1;
            if (kq < 30) w1 = *(const uint4*)(pw + 8192);
            pw += 4096;
            uint4 h0 = *(const uint4*)(&hp[0][kq * 4]);
            uint4 h1 = *(const uint4*)(&hp[1][kq * 4]);
            a0 = dot2f(h0.x, wc.x, a0); a1 = dot2f(h1.x, wc.x, a1);
            a0 = dot2f(h0.y, wc.y, a0); a1 = dot2f(h1.y, wc.y, a1);
            a0 = dot2f(h0.z, wc.z, a0); a1 = dot2f(h1.z, wc.z, a1);
            a0 = dot2f(h0.w, wc.w, a0); a1 = dot2f(h1.w, wc.w, a1);
        }
        gates[0][t] = a0 + xa;
        gates[1][t] = a1 + xb;
        __syncthreads();
        if (t < 512) {
            int bb = t >> 8, j = t & 255;
            float gi = gates[bb][j];
            float gf = gates[bb][256 + j];
            float gg = gates[bb][512 + j];
            float go = gates[bb][768 + j];
            float ii = sigf(gi), ff = sigf(gf), g2 = tanhf_(gg), oo = sigf(go);
            cst = ff * cst + ii * g2;
            float h = oo * tanhf_(cst);
            float hx = __shfl_xor(h, 1);
            if (!(t & 1)) {
                uint32_t pk = packh2(h, hx);
                hp[bb][j >> 1] = pk;
                size_t row = (size_t)(b0 + bb) * NS + te;
                outp[row * 256 + d * 128 + (j >> 1)] = pk;
            }
        }
        __syncthreads();
    }
}

// ------------- emissions: em[8192 x 5] = x2p @ out_w + out_b -----------------
__global__ __launch_bounds__(256) void emis_kernel(
    const uint32_t* __restrict__ x2p, const float* __restrict__ ow,
    const float* __restrict__ ob, float* __restrict__ em)
{
    int i = blockIdx.x * blockDim.x + threadIdx.x;
    if (i >= NB * NS) return;
    const uint32_t* xr = x2p + (size_t)i * 256;
    float acc[NLAB];
#pragma unroll
    for (int l = 0; l < NLAB; ++l) acc[l] = ob[l];
    for (int p = 0; p < 256; ++p) {
        h2_t hv = __builtin_bit_cast(h2_t, xr[p]);
        float lo = (float)hv[0], hi = (float)hv[1];
        int k = 2 * p;
#pragma unroll
        for (int l = 0; l < NLAB; ++l)
            acc[l] += lo * ow[(size_t)k * NLAB + l] + hi * ow[(size_t)(k + 1) * NLAB + l];
    }
    float* e = em + (size_t)i * NLAB;
#pragma unroll
    for (int l = 0; l < NLAB; ++l) e[l] = acc[l];
}

// ------------- CRF: numerator + forward algorithm + mean ---------------------
__device__ __forceinline__ float lse5(const float* v) {
    float m = fmaxf(fmaxf(fmaxf(v[0], v[1]), fmaxf(v[2], v[3])), v[4]);
    float s = __expf(v[0] - m) + __expf(v[1] - m) + __expf(v[2] - m) +
              __expf(v[3] - m) + __expf(v[4] - m);
    return m + __logf(s);
}

__global__ __launch_bounds__(64) void crf_kernel(
    const float* __restrict__ em, const int* __restrict__ labels,
    const int* __restrict__ lengths, const float* __restrict__ cstart,
    const float* __restrict__ cend, const float* __restrict__ ctrans,
    float* __restrict__ outp)
{
    __shared__ float tr_s[25], st_s[5], en_s[5];
    int tid = threadIdx.x;
    if (tid < 25) tr_s[tid] = ctrans[tid];
    if (tid < 5)  { st_s[tid] = cstart[tid]; en_s[tid] = cend[tid]; }
    __syncthreads();

    int b = tid;
    int len = lengths[b];
    const int* tg = labels + (size_t)b * NS;
    const float* eb = em + (size_t)b * NS * NLAB;

    int prev = tg[0];
    float num = st_s[prev] + eb[prev];
    for (int t = 1; t < NS; ++t) {
        if (t < len) {
            int cur = tg[t];
            num += tr_s[prev * NLAB + cur] + eb[t * NLAB + cur];
            prev = cur;
        }
    }
    num += en_s[tg[len - 1]];

    float a[NLAB];
#pragma unroll
    for (int y = 0; y < NLAB; ++y) a[y] = st_s[y] + eb[y];
    for (int t = 1; t < NS; ++t) {
        if (t < len) {
            float na[NLAB];
#pragma unroll
            for (int y = 0; y < NLAB; ++y) {
                float v[NLAB];
#pragma unroll
                for (int x = 0; x < NLAB; ++x) v[x] = a[x] + tr_s[x * NLAB + y];
                na[y] = lse5(v) + eb[t * NLAB + y];
            }
#pragma unroll
            for (int y = 0; y < NLAB; ++y) a[y] = na[y];
        }
    }
    float v[NLAB];
#pragma unroll
    for (int y = 0; y < NLAB; ++y) v[y] = a[y] + en_s[y];
    float denom = lse5(v);

    float llh = num - denom;
#pragma unroll
    for (int off = 32; off > 0; off >>= 1) llh += __shfl_down(llh, off);
    if (tid == 0) outp[0] = -llh * (1.0f / 64.0f);
}

// ----------------------------- launcher --------------------------------------
extern "C" void kernel_launch(void* const* d_in, const int* in_sizes, int n_in,
                              void* d_out, int out_size, void* d_ws, size_t ws_size,
                              hipStream_t stream)
{
    const int*   word_ids = (const int*)d_in[0];
    const int*   char_ids = (const int*)d_in[1];
    const int*   labels   = (const int*)d_in[2];
    const int*   lengths  = (const int*)d_in[3];
    const float* word_emb = (const float*)d_in[4];
    const float* char_emb = (const float*)d_in[5];
    const float* cw3 = (const float*)d_in[6];
    const float* cb3 = (const float*)d_in[7];
    const float* cw4 = (const float*)d_in[8];
    const float* cb4 = (const float*)d_in[9];
    const float* cw5 = (const float*)d_in[10];
    const float* cb5 = (const float*)d_in[11];
    const float* out_w = (const float*)d_in[12];
    const float* out_b = (const float*)d_in[13];
    const float* crf_start = (const float*)d_in[14];
    const float* crf_end   = (const float*)d_in[15];
    const float* crf_trans = (const float*)d_in[16];
    const float* Wih_l0f = (const float*)d_in[17];
    const float* Whh_l0f = (const float*)d_in[18];
    const float* b_l0f   = (const float*)d_in[19];
    const float* Wih_l0r = (const float*)d_in[20];
    const float* Whh_l0r = (const float*)d_in[21];
    const float* b_l0r   = (const float*)d_in[22];
    const float* Wih_l1f = (const float*)d_in[23];
    const float* Whh_l1f = (const float*)d_in[24];
    const float* b_l1f   = (const float*)d_in[25];
    const float* Wih_l1r = (const float*)d_in[26];
    const float* Whh_l1r = (const float*)d_in[27];
    const float* b_l1r   = (const float*)d_in[28];

    // workspace layout (4-byte units), total 24,365,056 = 97.5 MB
    uint32_t* wsu = (uint32_t*)d_ws;
    uint32_t* x0p  = wsu;                         // 8192*225  = 1,843,200
    float*    xg_f = (float*)(wsu + 1843200);     // 8192*1024 = 8,388,608
    float*    xg_r = xg_f + 8388608;
    uint32_t* x1p  = (uint32_t*)(xg_r + 8388608); // 8192*256  = 2,097,152
    uint32_t* x2p  = x1p + 2097152;               // 2,097,152
    float*    em   = (float*)(x2p + 2097152);     // 40,960
    uint32_t* wp0f = (uint32_t*)(em + 40960);     // 225*1024  = 230,400
    uint32_t* wp0r = wp0f + 230400;
    uint32_t* wp1f = wp0r + 230400;               // 256*1024  = 262,144
    uint32_t* wp1r = wp1f + 262144;
    uint32_t* wh0f = wp1r + 262144;               // 131,072 each
    uint32_t* wh0r = wh0f + 131072;
    uint32_t* wh1f = wh0r + 131072;
    uint32_t* wh1r = wh1f + 131072;

    cnn_embed<<<2048, 256, 0, stream>>>(word_ids, char_ids, word_emb, char_emb,
                                        cw3, cb3, cw4, cb4, cw5, cb5, x0p);

    pack_wih<<<900, 256, 0, stream>>>(Wih_l0f, COMB, wp0f);
    pack_wih<<<900, 256, 0, stream>>>(Wih_l0r, COMB, wp0r);
    pack_wih<<<1024, 256, 0, stream>>>(Wih_l1f, 512, wp1f);
    pack_wih<<<1024, 256, 0, stream>>>(Wih_l1r, 512, wp1r);
    pack_whh<<<512, 256, 0, stream>>>(Whh_l0f, wh0f);
    pack_whh<<<512, 256, 0, stream>>>(Whh_l0r, wh0r);
    pack_whh<<<512, 256, 0, stream>>>(Whh_l1f, wh1f);
    pack_whh<<<512, 256, 0, stream>>>(Whh_l1r, wh1r);

    dim3 gGemm(64, 16);
    gemm_f16<<<gGemm, 256, 0, stream>>>(x0p, 225, wp0f, wp0r, b_l0f, b_l0r, xg_f, xg_r);
    lstm_rec4<<<64, 1024, 0, stream>>>(xg_f, xg_r, wh0f, wh0r, x1p);

    gemm_f16<<<gGemm, 256, 0, stream>>>(x1p, 256, wp1f, wp1r, b_l1f, b_l1r, xg_f, xg_r);
    lstm_rec4<<<64, 1024, 0, stream>>>(xg_f, xg_r, wh1f, wh1r, x2p);

    emis_kernel<<<32, 256, 0, stream>>>(x2p, out_w, out_b, em);
    crf_kernel<<<1, 64, 0, stream>>>(em, labels, lengths, crf_start, crf_end, crf_trans,
                                     (float*)d_out);
}

// Round 5
// 1499.492 us; speedup vs baseline: 1.2566x; 1.2566x over previous
//
#include <hip/hip_runtime.h>
#include <hip/hip_fp16.h>
#include <math.h>
#include <stdint.h>

// Problem constants
#define NB   64      // batch
#define NS   128     // seq len
#define NW   16      // word length (chars)
#define CD   50      // char emb dim
#define NF_  50      // filters per kernel size
#define WD   300     // word emb dim
#define COMB 450     // WD + 3*NF  (even -> 225 f16 pairs)
#define HID  256
#define G4   1024    // 4*HID
#define NLAB 5

typedef _Float16 h2_t __attribute__((ext_vector_type(2)));

__device__ __forceinline__ float sigf(float x)   { return 1.0f / (1.0f + __expf(-x)); }
__device__ __forceinline__ float tanhf_(float x) { return 1.0f - 2.0f / (__expf(2.0f * x) + 1.0f); }

__device__ __forceinline__ float dot2f(uint32_t a, uint32_t b, float c) {
#if __has_builtin(__builtin_amdgcn_fdot2)
    return __builtin_amdgcn_fdot2(__builtin_bit_cast(h2_t, a),
                                  __builtin_bit_cast(h2_t, b), c, false);
#else
    h2_t ah = __builtin_bit_cast(h2_t, a), bh = __builtin_bit_cast(h2_t, b);
    return c + (float)ah[0] * (float)bh[0] + (float)ah[1] * (float)bh[1];
#endif
}

__device__ __forceinline__ uint32_t packh2(float lo, float hi) {
    __half l = __float2half(lo), h = __float2half(hi);
    return ((uint32_t)__half_as_ushort(h) << 16) | (uint32_t)__half_as_ushort(l);
}

// ---------------- CNN + embedding concat -> x0p (8192 x 225 u32, f16 pairs) --
__global__ __launch_bounds__(256) void cnn_embed(
    const int* __restrict__ word_ids, const int* __restrict__ char_ids,
    const float* __restrict__ word_emb, const float* __restrict__ char_emb,
    const float* __restrict__ w3, const float* __restrict__ b3,
    const float* __restrict__ w4, const float* __restrict__ b4,
    const float* __restrict__ w5, const float* __restrict__ b5,
    uint32_t* __restrict__ x0p)
{
    __shared__ float ce[4][NW][CD];
    __shared__ float cv[4][152];            // conv outputs per position
    int tid  = threadIdx.x;
    int g    = tid >> 6;
    int lane = tid & 63;
    int pos  = blockIdx.x * 4 + g;          // 0..8191

    const int* cid = char_ids + (size_t)pos * NW;
    for (int idx = lane; idx < NW * CD; idx += 64) {
        int w  = idx / CD;
        int cc = idx - w * CD;
        ce[g][w][cc] = char_emb[(size_t)cid[w] * CD + cc];
    }
    // word embedding -> packed pairs 0..149
    {
        int wid = word_ids[pos];
        const float* src = word_emb + (size_t)wid * WD;
        uint32_t* dst = x0p + (size_t)pos * 225;
        for (int idx = lane; idx < 150; idx += 64) {
            float2 v = *(const float2*)(src + 2 * idx);
            dst[idx] = packh2(v.x, v.y);
        }
    }
    __syncthreads();

    int f = lane;
    if (f < NF_) {
        float a3[16], a4[17], a5[16];
        float bb3 = b3[f], bb4 = b4[f], bb5 = b5[f];
#pragma unroll
        for (int p = 0; p < 16; ++p) { a3[p] = bb3; a5[p] = bb5; }
#pragma unroll
        for (int p = 0; p < 17; ++p) a4[p] = bb4;

        for (int c = 0; c < CD; ++c) {
            float w3r[3], w4r[4], w5r[5];
#pragma unroll
            for (int t = 0; t < 3; ++t) w3r[t] = w3[(t * CD + c) * NF_ + f];
#pragma unroll
            for (int t = 0; t < 4; ++t) w4r[t] = w4[(t * CD + c) * NF_ + f];
#pragma unroll
            for (int t = 0; t < 5; ++t) w5r[t] = w5[(t * CD + c) * NF_ + f];
#pragma unroll
            for (int ip = 0; ip < 16; ++ip) {
                float v = ce[g][ip][c];
#pragma unroll
                for (int t = 0; t < 3; ++t) { int p = ip + 1 - t; if (p >= 0 && p < 16) a3[p] += v * w3r[t]; }
#pragma unroll
                for (int t = 0; t < 4; ++t) { int p = ip + 2 - t; if (p >= 0 && p < 17) a4[p] += v * w4r[t]; }
#pragma unroll
                for (int t = 0; t < 5; ++t) { int p = ip + 2 - t; if (p >= 0 && p < 16) a5[p] += v * w5r[t]; }
            }
        }
        float m3 = 0.f, m4 = 0.f, m5 = 0.f;
#pragma unroll
        for (int p = 0; p < 16; ++p) m3 = fmaxf(m3, a3[p]);
#pragma unroll
        for (int p = 0; p < 17; ++p) m4 = fmaxf(m4, a4[p]);
#pragma unroll
        for (int p = 0; p < 16; ++p) m5 = fmaxf(m5, a5[p]);
        cv[g][f] = m3; cv[g][50 + f] = m4; cv[g][100 + f] = m5;
    }
    __syncthreads();
    // pack conv pairs 150..224
    {
        uint32_t* dst = x0p + (size_t)pos * 225 + 150;
        for (int idx = lane; idx < 75; idx += 64)
            dst[idx] = packh2(cv[g][2 * idx], cv[g][2 * idx + 1]);
    }
}

// ------------- weight packs ---------------------------------------------------
// Wih: P[kp*1024 + n] = h2(W[2kp][n], W[2kp+1][n])
__global__ __launch_bounds__(256) void pack_wih(
    const float* __restrict__ W, int K, uint32_t* __restrict__ P)
{
    int idx = blockIdx.x * 256 + threadIdx.x;
    int K2 = K >> 1;
    if (idx >= K2 * 1024) return;
    int n = idx & 1023, kp = idx >> 10;
    int k0 = 2 * kp;
    float lo = W[(size_t)k0 * 1024 + n];
    float hi = W[(size_t)(k0 + 1) * 1024 + n];
    P[idx] = packh2(lo, hi);
}

// Whh: P[(kq*1024+col)*4+kk] = h2(W[8kq+2kk][col], W[8kq+2kk+1][col])
__global__ __launch_bounds__(256) void pack_whh(
    const float* __restrict__ W, uint32_t* __restrict__ P)
{
    int idx = blockIdx.x * 256 + threadIdx.x;     // 32*1024*4 = 131072
    if (idx >= 131072) return;
    int kk = idx & 3, col = (idx >> 2) & 1023, kq = idx >> 12;
    int k = kq * 8 + kk * 2;
    float lo = W[(size_t)k * G4 + col];
    float hi = W[(size_t)(k + 1) * G4 + col];
    P[idx] = packh2(lo, hi);
}

// ------------- xg GEMM (f16 dot2): C[8192 x 1024] = Ap @ Wp + bias -----------
__global__ __launch_bounds__(256) void gemm_f16(
    const uint32_t* __restrict__ Ap, int K2,
    const uint32_t* __restrict__ Wpf, const uint32_t* __restrict__ Wpr,
    const float* __restrict__ bf, const float* __restrict__ br,
    float* __restrict__ Cf, float* __restrict__ Cr)
{
    int by  = blockIdx.y;
    int dir = by >> 3;
    int n0  = (by & 7) * 128;
    int m0  = blockIdx.x * 128;
    const uint32_t* Wp = dir ? Wpr : Wpf;
    const float* bias  = dir ? br : bf;
    float* C           = dir ? Cr : Cf;

    __shared__ uint32_t As[8][132];
    __shared__ uint32_t Bs[8][132];

    int tid = threadIdx.x;
    int ka = tid & 7,  ma = tid >> 3;       // A: 8 kp x 32 rows (x4)
    int kb = tid >> 7, nb = tid & 127;      // B: 2 kp (x4) x 128 n
    int tx = tid & 15, ty = tid >> 4;
    int row0 = ty * 8, col0 = tx * 8;

    float acc[8][8] = {};

    for (int kp0 = 0; kp0 < K2; kp0 += 8) {
#pragma unroll
        for (int i = 0; i < 4; ++i) {
            uint32_t v = 0;
            if (kp0 + ka < K2) v = Ap[(size_t)(m0 + ma + 32 * i) * K2 + kp0 + ka];
            As[ka][ma + 32 * i] = v;
        }
#pragma unroll
        for (int i = 0; i < 4; ++i) {
            int kp = kb + 2 * i;
            uint32_t v = 0;
            if (kp0 + kp < K2) v = Wp[(size_t)(kp0 + kp) * G4 + n0 + nb];
            Bs[kp][nb] = v;
        }
        __syncthreads();
#pragma unroll
        for (int kp = 0; kp < 8; ++kp) {
            uint32_t a[8], b[8];
            *(uint4*)&a[0] = *(const uint4*)&As[kp][row0];
            *(uint4*)&a[4] = *(const uint4*)&As[kp][row0 + 4];
            *(uint4*)&b[0] = *(const uint4*)&Bs[kp][col0];
            *(uint4*)&b[4] = *(const uint4*)&Bs[kp][col0 + 4];
#pragma unroll
            for (int i = 0; i < 8; ++i)
#pragma unroll
                for (int j = 0; j < 8; ++j)
                    acc[i][j] = dot2f(a[i], b[j], acc[i][j]);
        }
        __syncthreads();
    }
#pragma unroll
    for (int i = 0; i < 8; ++i) {
        size_t crow = (size_t)(m0 + row0 + i) * G4 + n0 + col0;
#pragma unroll
        for (int j = 0; j < 8; j += 4) {
            float4 o;
            o.x = acc[i][j]     + bias[n0 + col0 + j];
            o.y = acc[i][j + 1] + bias[n0 + col0 + j + 1];
            o.z = acc[i][j + 2] + bias[n0 + col0 + j + 2];
            o.w = acc[i][j + 3] + bias[n0 + col0 + j + 3];
            *(float4*)&C[crow + j] = o;
        }
    }
}

// ------------- LSTM recurrence v5: 64 blocks x 512 thr ------------------------
// Three-tier Whh residency: k-pairs [0,64) in VGPR (loaded once), [64,96)
// streamed from L2 per step, [96,128) in LDS (filled once). h broadcast via
// v_readlane (VALU pipe) instead of LDS-broadcast reads (which bound rec4 at
// 12K LDS-pipe cyc/step). Thread owns cols {t, t+512} for both batch rows.
#define DOT1(LANE, HLO, HHI, WA, WB) { \
    uint32_t h0_ = (uint32_t)__builtin_amdgcn_readlane((HLO), (LANE)); \
    uint32_t h1_ = (uint32_t)__builtin_amdgcn_readlane((HHI), (LANE)); \
    aA0 = dot2f(h0_, (WA), aA0); aA1 = dot2f(h1_, (WA), aA1); \
    aB0 = dot2f(h0_, (WB), aB0); aB1 = dot2f(h1_, (WB), aB1); }

#define DOTQ(LB, HLO, HHI, WQA, WQB) \
    DOT1((LB) + 0, HLO, HHI, (WQA).x, (WQB).x) \
    DOT1((LB) + 1, HLO, HHI, (WQA).y, (WQB).y) \
    DOT1((LB) + 2, HLO, HHI, (WQA).z, (WQB).z) \
    DOT1((LB) + 3, HLO, HHI, (WQA).w, (WQB).w)

__global__ __launch_bounds__(512, 2) void lstm_rec5(
    const float* __restrict__ xg_f, const float* __restrict__ xg_r,
    const uint32_t* __restrict__ Pf, const uint32_t* __restrict__ Pr,
    uint32_t* __restrict__ outp)   // [8192][256] u32: row*256 + d*128 + jp
{
    int bid = blockIdx.x;           // 64 = 32 batch-pairs x 2 dirs
    int bp = bid >> 1, d = bid & 1;
    int b0 = 2 * bp;
    const float* xg = d ? xg_r : xg_f;
    const uint4* P4 = (const uint4*)(d ? Pr : Pf);   // [kq*1024 + col]

    __shared__ alignas(16) uint32_t hp[256];    // [row*128 + k2] packed f16 h
    __shared__ float gates[2][G4];
    __shared__ alignas(16) uint4 Tl[8 * 1024];  // kq 24..31, all cols (128 KB)

    int t = threadIdx.x;            // 0..511
    int lane = t & 63;

    // fill LDS weight tier (once)
    for (int i = t; i < 8192; i += 512) Tl[i] = P4[24 * 1024 + i];
    if (t < 256) hp[t] = 0;
    float cst = 0.f;                // cell state for (bb=t>>8, j=t&255)

    // VGPR weight tier: kq 0..15, cols t and t+512 (lives across all steps)
    uint4 wA[16], wB[16];
#pragma unroll
    for (int kq = 0; kq < 16; ++kq) {
        wA[kq] = P4[kq * 1024 + t];
        wB[kq] = P4[kq * 1024 + t + 512];
    }
    __syncthreads();

    for (int s = 0; s < NS; ++s) {
        int te = d ? (NS - 1 - s) : s;
        size_t r0 = ((size_t)b0 * NS + te) * G4;
        size_t r1 = r0 + (size_t)NS * G4;
        // xg loads issued early; first use after the dot loops
        float xA0 = xg[r0 + t], xB0 = xg[r0 + 512 + t];
        float xA1 = xg[r1 + t], xB1 = xg[r1 + 512 + t];

        // streamed tier: kq 16..23 (issued up front, consumed mid-step)
        uint4 sA[8], sB[8];
#pragma unroll
        for (int i = 0; i < 8; ++i) {
            sA[i] = P4[(16 + i) * 1024 + t];
            sB[i] = P4[(16 + i) * 1024 + t + 512];
        }

        // h into per-wave registers (4 conflict-free ds_read_b32)
        const int* hpi = (const int*)hp;
        int hr0 = hpi[lane];         // row0 k2 [0,64)
        int hr1 = hpi[64 + lane];    // row0 k2 [64,128)
        int hr2 = hpi[128 + lane];   // row1 k2 [0,64)
        int hr3 = hpi[192 + lane];   // row1 k2 [64,128)

        float aA0 = 0.f, aA1 = 0.f, aB0 = 0.f, aB1 = 0.f;

        // tier 1: VGPR-resident, k2 in [0,64)
#pragma unroll
        for (int kq = 0; kq < 16; ++kq) {
            DOTQ(4 * kq, hr0, hr2, wA[kq], wB[kq])
        }
        // tier 2: streamed, k2 in [64,96) -> lanes 0..31 of hr1/hr3
#pragma unroll
        for (int kq = 0; kq < 8; ++kq) {
            DOTQ(4 * kq, hr1, hr3, sA[kq], sB[kq])
        }
        // tier 3: LDS-resident, k2 in [96,128) -> lanes 32..63 of hr1/hr3
#pragma unroll
        for (int kq = 0; kq < 8; ++kq) {
            uint4 ta = Tl[kq * 1024 + t];
            uint4 tb = Tl[kq * 1024 + t + 512];
            DOTQ(32 + 4 * kq, hr1, hr3, ta, tb)
        }

        gates[0][t]       = aA0 + xA0;
        gates[0][t + 512] = aB0 + xB0;
        gates[1][t]       = aA1 + xA1;
        gates[1][t + 512] = aB1 + xB1;
        __syncthreads();
        {
            int bb = t >> 8, j = t & 255;
            float gi = gates[bb][j];
            float gf = gates[bb][256 + j];
            float gg = gates[bb][512 + j];
            float go = gates[bb][768 + j];
            float ii = sigf(gi), ff = sigf(gf), g2 = tanhf_(gg), oo = sigf(go);
            cst = ff * cst + ii * g2;
            float h = oo * tanhf_(cst);
            float hx = __shfl_xor(h, 1);
            if (!(t & 1)) {
                uint32_t pk = packh2(h, hx);
                hp[bb * 128 + (j >> 1)] = pk;
                size_t row = (size_t)(b0 + bb) * NS + te;
                outp[row * 256 + d * 128 + (j >> 1)] = pk;
            }
        }
        __syncthreads();
    }
}

// ------------- emissions: em[8192 x 5] = x2p @ out_w + out_b -----------------
__global__ __launch_bounds__(256) void emis_kernel(
    const uint32_t* __restrict__ x2p, const float* __restrict__ ow,
    const float* __restrict__ ob, float* __restrict__ em)
{
    int i = blockIdx.x * blockDim.x + threadIdx.x;
    if (i >= NB * NS) return;
    const uint32_t* xr = x2p + (size_t)i * 256;
    float acc[NLAB];
#pragma unroll
    for (int l = 0; l < NLAB; ++l) acc[l] = ob[l];
    for (int p = 0; p < 256; ++p) {
        h2_t hv = __builtin_bit_cast(h2_t, xr[p]);
        float lo = (float)hv[0], hi = (float)hv[1];
        int k = 2 * p;
#pragma unroll
        for (int l = 0; l < NLAB; ++l)
            acc[l] += lo * ow[(size_t)k * NLAB + l] + hi * ow[(size_t)(k + 1) * NLAB + l];
    }
    float* e = em + (size_t)i * NLAB;
#pragma unroll
    for (int l = 0; l < NLAB; ++l) e[l] = acc[l];
}

// ------------- CRF: numerator + forward algorithm + mean ---------------------
__device__ __forceinline__ float lse5(const float* v) {
    float m = fmaxf(fmaxf(fmaxf(v[0], v[1]), fmaxf(v[2], v[3])), v[4]);
    float s = __expf(v[0] - m) + __expf(v[1] - m) + __expf(v[2] - m) +
              __expf(v[3] - m) + __expf(v[4] - m);
    return m + __logf(s);
}

__global__ __launch_bounds__(64) void crf_kernel(
    const float* __restrict__ em, const int* __restrict__ labels,
    const int* __restrict__ lengths, const float* __restrict__ cstart,
    const float* __restrict__ cend, const float* __restrict__ ctrans,
    float* __restrict__ outp)
{
    __shared__ float tr_s[25], st_s[5], en_s[5];
    int tid = threadIdx.x;
    if (tid < 25) tr_s[tid] = ctrans[tid];
    if (tid < 5)  { st_s[tid] = cstart[tid]; en_s[tid] = cend[tid]; }
    __syncthreads();

    int b = tid;
    int len = lengths[b];
    const int* tg = labels + (size_t)b * NS;
    const float* eb = em + (size_t)b * NS * NLAB;

    int prev = tg[0];
    float num = st_s[prev] + eb[prev];
    for (int t = 1; t < NS; ++t) {
        if (t < len) {
            int cur = tg[t];
            num += tr_s[prev * NLAB + cur] + eb[t * NLAB + cur];
            prev = cur;
        }
    }
    num += en_s[tg[len - 1]];

    float a[NLAB];
#pragma unroll
    for (int y = 0; y < NLAB; ++y) a[y] = st_s[y] + eb[y];
    for (int t = 1; t < NS; ++t) {
        if (t < len) {
            float na[NLAB];
#pragma unroll
            for (int y = 0; y < NLAB; ++y) {
                float v[NLAB];
#pragma unroll
                for (int x = 0; x < NLAB; ++x) v[x] = a[x] + tr_s[x * NLAB + y];
                na[y] = lse5(v) + eb[t * NLAB + y];
            }
#pragma unroll
            for (int y = 0; y < NLAB; ++y) a[y] = na[y];
        }
    }
    float v[NLAB];
#pragma unroll
    for (int y = 0; y < NLAB; ++y) v[y] = a[y] + en_s[y];
    float denom = lse5(v);

    float llh = num - denom;
#pragma unroll
    for (int off = 32; off > 0; off >>= 1) llh += __shfl_down(llh, off);
    if (tid == 0) outp[0] = -llh * (1.0f / 64.0f);
}

// ----------------------------- launcher --------------------------------------
extern "C" void kernel_launch(void* const* d_in, const int* in_sizes, int n_in,
                              void* d_out, int out_size, void* d_ws, size_t ws_size,
                              hipStream_t stream)
{
    const int*   word_ids = (const int*)d_in[0];
    const int*   char_ids = (const int*)d_in[1];
    const int*   labels   = (const int*)d_in[2];
    const int*   lengths  = (const int*)d_in[3];
    const float* word_emb = (const float*)d_in[4];
    const float* char_emb = (const float*)d_in[5];
    const float* cw3 = (const float*)d_in[6];
    const float* cb3 = (const float*)d_in[7];
    const float* cw4 = (const float*)d_in[8];
    const float* cb4 = (const float*)d_in[9];
    const float* cw5 = (const float*)d_in[10];
    const float* cb5 = (const float*)d_in[11];
    const float* out_w = (const float*)d_in[12];
    const float* out_b = (const float*)d_in[13];
    const float* crf_start = (const float*)d_in[14];
    const float* crf_end   = (const float*)d_in[15];
    const float* crf_trans = (const float*)d_in[16];
    const float* Wih_l0f = (const float*)d_in[17];
    const float* Whh_l0f = (const float*)d_in[18];
    const float* b_l0f   = (const float*)d_in[19];
    const float* Wih_l0r = (const float*)d_in[20];
    const float* Whh_l0r = (const float*)d_in[21];
    const float* b_l0r   = (const float*)d_in[22];
    const float* Wih_l1f = (const float*)d_in[23];
    const float* Whh_l1f = (const float*)d_in[24];
    const float* b_l1f   = (const float*)d_in[25];
    const float* Wih_l1r = (const float*)d_in[26];
    const float* Whh_l1r = (const float*)d_in[27];
    const float* b_l1r   = (const float*)d_in[28];

    // workspace layout (4-byte units), total 24,365,056 = 97.5 MB
    uint32_t* wsu = (uint32_t*)d_ws;
    uint32_t* x0p  = wsu;                         // 8192*225  = 1,843,200
    float*    xg_f = (float*)(wsu + 1843200);     // 8192*1024 = 8,388,608
    float*    xg_r = xg_f + 8388608;
    uint32_t* x1p  = (uint32_t*)(xg_r + 8388608); // 8192*256  = 2,097,152
    uint32_t* x2p  = x1p + 2097152;               // 2,097,152
    float*    em   = (float*)(x2p + 2097152);     // 40,960
    uint32_t* wp0f = (uint32_t*)(em + 40960);     // 225*1024  = 230,400
    uint32_t* wp0r = wp0f + 230400;
    uint32_t* wp1f = wp0r + 230400;               // 256*1024  = 262,144
    uint32_t* wp1r = wp1f + 262144;
    uint32_t* wh0f = wp1r + 262144;               // 131,072 each
    uint32_t* wh0r = wh0f + 131072;
    uint32_t* wh1f = wh0r + 131072;
    uint32_t* wh1r = wh1f + 131072;

    cnn_embed<<<2048, 256, 0, stream>>>(word_ids, char_ids, word_emb, char_emb,
                                        cw3, cb3, cw4, cb4, cw5, cb5, x0p);

    pack_wih<<<900, 256, 0, stream>>>(Wih_l0f, COMB, wp0f);
    pack_wih<<<900, 256, 0, stream>>>(Wih_l0r, COMB, wp0r);
    pack_wih<<<1024, 256, 0, stream>>>(Wih_l1f, 512, wp1f);
    pack_wih<<<1024, 256, 0, stream>>>(Wih_l1r, 512, wp1r);
    pack_whh<<<512, 256, 0, stream>>>(Whh_l0f, wh0f);
    pack_whh<<<512, 256, 0, stream>>>(Whh_l0r, wh0r);
    pack_whh<<<512, 256, 0, stream>>>(Whh_l1f, wh1f);
    pack_whh<<<512, 256, 0, stream>>>(Whh_l1r, wh1r);

    dim3 gGemm(64, 16);
    gemm_f16<<<gGemm, 256, 0, stream>>>(x0p, 225, wp0f, wp0r, b_l0f, b_l0r, xg_f, xg_r);
    lstm_rec5<<<64, 512, 0, stream>>>(xg_f, xg_r, wh0f, wh0r, x1p);

    gemm_f16<<<gGemm, 256, 0, stream>>>(x1p, 256, wp1f, wp1r, b_l1f, b_l1r, xg_f, xg_r);
    lstm_rec5<<<64, 512, 0, stream>>>(xg_f, xg_r, wh1f, wh1r, x2p);

    emis_kernel<<<32, 256, 0, stream>>>(x2p, out_w, out_b, em);
    crf_kernel<<<1, 64, 0, stream>>>(em, labels, lengths, crf_start, crf_end, crf_trans,
                                     (float*)d_out);
}

// Round 6
// 1184.342 us; speedup vs baseline: 1.5909x; 1.2661x over previous
//
#include <hip/hip_runtime.h>
#include <hip/hip_fp16.h>
#include <math.h>
#include <stdint.h>

// Problem constants
#define NB   64      // batch
#define NS   128     // seq len
#define NW   16      // word length (chars)
#define CD   50      // char emb dim
#define NF_  50      // filters per kernel size
#define WD   300     // word emb dim
#define COMB 450     // WD + 3*NF  (even -> 225 f16 pairs)
#define HID  256
#define G4   1024    // 4*HID
#define NLAB 5

typedef _Float16 h2_t __attribute__((ext_vector_type(2)));

__device__ __forceinline__ float sigf(float x)   { return 1.0f / (1.0f + __expf(-x)); }
__device__ __forceinline__ float tanhf_(float x) { return 1.0f - 2.0f / (__expf(2.0f * x) + 1.0f); }

__device__ __forceinline__ float dot2f(uint32_t a, uint32_t b, float c) {
#if __has_builtin(__builtin_amdgcn_fdot2)
    return __builtin_amdgcn_fdot2(__builtin_bit_cast(h2_t, a),
                                  __builtin_bit_cast(h2_t, b), c, false);
#else
    h2_t ah = __builtin_bit_cast(h2_t, a), bh = __builtin_bit_cast(h2_t, b);
    return c + (float)ah[0] * (float)bh[0] + (float)ah[1] * (float)bh[1];
#endif
}

__device__ __forceinline__ uint32_t packh2(float lo, float hi) {
    __half l = __float2half(lo), h = __float2half(hi);
    return ((uint32_t)__half_as_ushort(h) << 16) | (uint32_t)__half_as_ushort(l);
}

// ---------------- CNN + embedding concat -> x0p (8192 x 225 u32, f16 pairs) --
__global__ __launch_bounds__(256) void cnn_embed(
    const int* __restrict__ word_ids, const int* __restrict__ char_ids,
    const float* __restrict__ word_emb, const float* __restrict__ char_emb,
    const float* __restrict__ w3, const float* __restrict__ b3,
    const float* __restrict__ w4, const float* __restrict__ b4,
    const float* __restrict__ w5, const float* __restrict__ b5,
    uint32_t* __restrict__ x0p)
{
    __shared__ float ce[4][NW][CD];
    __shared__ float cv[4][152];            // conv outputs per position
    int tid  = threadIdx.x;
    int g    = tid >> 6;
    int lane = tid & 63;
    int pos  = blockIdx.x * 4 + g;          // 0..8191

    const int* cid = char_ids + (size_t)pos * NW;
    for (int idx = lane; idx < NW * CD; idx += 64) {
        int w  = idx / CD;
        int cc = idx - w * CD;
        ce[g][w][cc] = char_emb[(size_t)cid[w] * CD + cc];
    }
    // word embedding -> packed pairs 0..149
    {
        int wid = word_ids[pos];
        const float* src = word_emb + (size_t)wid * WD;
        uint32_t* dst = x0p + (size_t)pos * 225;
        for (int idx = lane; idx < 150; idx += 64) {
            float2 v = *(const float2*)(src + 2 * idx);
            dst[idx] = packh2(v.x, v.y);
        }
    }
    __syncthreads();

    int f = lane;
    if (f < NF_) {
        float a3[16], a4[17], a5[16];
        float bb3 = b3[f], bb4 = b4[f], bb5 = b5[f];
#pragma unroll
        for (int p = 0; p < 16; ++p) { a3[p] = bb3; a5[p] = bb5; }
#pragma unroll
        for (int p = 0; p < 17; ++p) a4[p] = bb4;

        for (int c = 0; c < CD; ++c) {
            float w3r[3], w4r[4], w5r[5];
#pragma unroll
            for (int t = 0; t < 3; ++t) w3r[t] = w3[(t * CD + c) * NF_ + f];
#pragma unroll
            for (int t = 0; t < 4; ++t) w4r[t] = w4[(t * CD + c) * NF_ + f];
#pragma unroll
            for (int t = 0; t < 5; ++t) w5r[t] = w5[(t * CD + c) * NF_ + f];
#pragma unroll
            for (int ip = 0; ip < 16; ++ip) {
                float v = ce[g][ip][c];
#pragma unroll
                for (int t = 0; t < 3; ++t) { int p = ip + 1 - t; if (p >= 0 && p < 16) a3[p] += v * w3r[t]; }
#pragma unroll
                for (int t = 0; t < 4; ++t) { int p = ip + 2 - t; if (p >= 0 && p < 17) a4[p] += v * w4r[t]; }
#pragma unroll
                for (int t = 0; t < 5; ++t) { int p = ip + 2 - t; if (p >= 0 && p < 16) a5[p] += v * w5r[t]; }
            }
        }
        float m3 = 0.f, m4 = 0.f, m5 = 0.f;
#pragma unroll
        for (int p = 0; p < 16; ++p) m3 = fmaxf(m3, a3[p]);
#pragma unroll
        for (int p = 0; p < 17; ++p) m4 = fmaxf(m4, a4[p]);
#pragma unroll
        for (int p = 0; p < 16; ++p) m5 = fmaxf(m5, a5[p]);
        cv[g][f] = m3; cv[g][50 + f] = m4; cv[g][100 + f] = m5;
    }
    __syncthreads();
    // pack conv pairs 150..224
    {
        uint32_t* dst = x0p + (size_t)pos * 225 + 150;
        for (int idx = lane; idx < 75; idx += 64)
            dst[idx] = packh2(cv[g][2 * idx], cv[g][2 * idx + 1]);
    }
}

// ------------- weight packs ---------------------------------------------------
// Wih: P[kp*1024 + n] = h2(W[2kp][n], W[2kp+1][n])
__global__ __launch_bounds__(256) void pack_wih(
    const float* __restrict__ W, int K, uint32_t* __restrict__ P)
{
    int idx = blockIdx.x * 256 + threadIdx.x;
    int K2 = K >> 1;
    if (idx >= K2 * 1024) return;
    int n = idx & 1023, kp = idx >> 10;
    int k0 = 2 * kp;
    float lo = W[(size_t)k0 * 1024 + n];
    float hi = W[(size_t)(k0 + 1) * 1024 + n];
    P[idx] = packh2(lo, hi);
}

// Whh: P[(kq*1024+col)*4+kk] = h2(W[8kq+2kk][col], W[8kq+2kk+1][col])
__global__ __launch_bounds__(256) void pack_whh(
    const float* __restrict__ W, uint32_t* __restrict__ P)
{
    int idx = blockIdx.x * 256 + threadIdx.x;     // 32*1024*4 = 131072
    if (idx >= 131072) return;
    int kk = idx & 3, col = (idx >> 2) & 1023, kq = idx >> 12;
    int k = kq * 8 + kk * 2;
    float lo = W[(size_t)k * G4 + col];
    float hi = W[(size_t)(k + 1) * G4 + col];
    P[idx] = packh2(lo, hi);
}

// ------------- xg GEMM (f16 dot2): C[8192 x 1024] = Ap @ Wp + bias -----------
__global__ __launch_bounds__(256) void gemm_f16(
    const uint32_t* __restrict__ Ap, int K2,
    const uint32_t* __restrict__ Wpf, const uint32_t* __restrict__ Wpr,
    const float* __restrict__ bf, const float* __restrict__ br,
    float* __restrict__ Cf, float* __restrict__ Cr)
{
    int by  = blockIdx.y;
    int dir = by >> 3;
    int n0  = (by & 7) * 128;
    int m0  = blockIdx.x * 128;
    const uint32_t* Wp = dir ? Wpr : Wpf;
    const float* bias  = dir ? br : bf;
    float* C           = dir ? Cr : Cf;

    __shared__ uint32_t As[8][132];
    __shared__ uint32_t Bs[8][132];

    int tid = threadIdx.x;
    int ka = tid & 7,  ma = tid >> 3;       // A: 8 kp x 32 rows (x4)
    int kb = tid >> 7, nb = tid & 127;      // B: 2 kp (x4) x 128 n
    int tx = tid & 15, ty = tid >> 4;
    int row0 = ty * 8, col0 = tx * 8;

    float acc[8][8] = {};

    for (int kp0 = 0; kp0 < K2; kp0 += 8) {
#pragma unroll
        for (int i = 0; i < 4; ++i) {
            uint32_t v = 0;
            if (kp0 + ka < K2) v = Ap[(size_t)(m0 + ma + 32 * i) * K2 + kp0 + ka];
            As[ka][ma + 32 * i] = v;
        }
#pragma unroll
        for (int i = 0; i < 4; ++i) {
            int kp = kb + 2 * i;
            uint32_t v = 0;
            if (kp0 + kp < K2) v = Wp[(size_t)(kp0 + kp) * G4 + n0 + nb];
            Bs[kp][nb] = v;
        }
        __syncthreads();
#pragma unroll
        for (int kp = 0; kp < 8; ++kp) {
            uint32_t a[8], b[8];
            *(uint4*)&a[0] = *(const uint4*)&As[kp][row0];
            *(uint4*)&a[4] = *(const uint4*)&As[kp][row0 + 4];
            *(uint4*)&b[0] = *(const uint4*)&Bs[kp][col0];
            *(uint4*)&b[4] = *(const uint4*)&Bs[kp][col0 + 4];
#pragma unroll
            for (int i = 0; i < 8; ++i)
#pragma unroll
                for (int j = 0; j < 8; ++j)
                    acc[i][j] = dot2f(a[i], b[j], acc[i][j]);
        }
        __syncthreads();
    }
#pragma unroll
    for (int i = 0; i < 8; ++i) {
        size_t crow = (size_t)(m0 + row0 + i) * G4 + n0 + col0;
#pragma unroll
        for (int j = 0; j < 8; j += 4) {
            float4 o;
            o.x = acc[i][j]     + bias[n0 + col0 + j];
            o.y = acc[i][j + 1] + bias[n0 + col0 + j + 1];
            o.z = acc[i][j + 2] + bias[n0 + col0 + j + 2];
            o.w = acc[i][j + 3] + bias[n0 + col0 + j + 3];
            *(float4*)&C[crow + j] = o;
        }
    }
}

// ------------- LSTM recurrence v6: 128 blocks x 512 thr -----------------------
// Block per (batch, dir). Thread owns cols {t, t+512} for ONE batch row.
// Whh residency: k-pairs [0,96) truly VGPR-resident (volatile loads -> compiler
// cannot rematerialize; rec5's non-volatile "tier" was silently re-streamed,
// VGPR_Count=116 < the 128 the tier needed), k-pairs [96,128) in LDS (128 KB).
// h broadcast via v_readlane (VALU pipe). Zero per-step L2 weight traffic.
#define DOT1(LANE, HREG, WA, WB) { \
    uint32_t h_ = (uint32_t)__builtin_amdgcn_readlane((HREG), (LANE)); \
    a0 = dot2f(h_, (WA), a0); a1 = dot2f(h_, (WB), a1); }

#define DOTQ(LB, HREG, WQA, WQB) \
    DOT1((LB) + 0, HREG, (WQA).x, (WQB).x) \
    DOT1((LB) + 1, HREG, (WQA).y, (WQB).y) \
    DOT1((LB) + 2, HREG, (WQA).z, (WQB).z) \
    DOT1((LB) + 3, HREG, (WQA).w, (WQB).w)

__global__ __launch_bounds__(512, 2) void lstm_rec6(
    const float* __restrict__ xg_f, const float* __restrict__ xg_r,
    const uint32_t* __restrict__ Pf, const uint32_t* __restrict__ Pr,
    uint32_t* __restrict__ outp)   // [8192][256] u32: row*256 + d*128 + jp
{
    int bid = blockIdx.x;           // 128 = 64 batches x 2 dirs
    int b = bid >> 1, d = bid & 1;
    const float* xg = d ? xg_r : xg_f;
    const uint4* P4 = (const uint4*)(d ? Pr : Pf);   // [kq*1024 + col]

    __shared__ alignas(16) uint32_t hp[128];    // packed f16 h pairs (1 row)
    __shared__ float gates[G4];
    __shared__ alignas(16) uint4 Tl[8 * 1024];  // kq 24..31, all cols (128 KB)

    int t = threadIdx.x;            // 0..511
    int lane = t & 63;

    // fill LDS weight tier (once)
    for (int i = t; i < 8192; i += 512) Tl[i] = P4[24 * 1024 + i];
    if (t < 128) hp[t] = 0;
    float cst = 0.f;                // cell state for j=t (threads 0..255)

    // VGPR tier: kq 0..23 (k-pairs 0..95), cols t and t+512.
    // volatile: forces the values to stay in registers (non-rematerializable).
    volatile const uint4* P4v = P4;
    uint4 wA[24], wB[24];
#pragma unroll
    for (int kq = 0; kq < 24; ++kq) {
        uint4 va, vb;
        va.x = P4v[kq * 1024 + t].x;        va.y = P4v[kq * 1024 + t].y;
        va.z = P4v[kq * 1024 + t].z;        va.w = P4v[kq * 1024 + t].w;
        vb.x = P4v[kq * 1024 + t + 512].x;  vb.y = P4v[kq * 1024 + t + 512].y;
        vb.z = P4v[kq * 1024 + t + 512].z;  vb.w = P4v[kq * 1024 + t + 512].w;
        wA[kq] = va; wB[kq] = vb;
    }
    __syncthreads();

    for (int s = 0; s < NS; ++s) {
        int te = d ? (NS - 1 - s) : s;
        int row = b * NS + te;
        size_t r0 = (size_t)row * G4;
        float xA = xg[r0 + t];       // issued early, used after dot loop
        float xB = xg[r0 + 512 + t];

        // h into per-wave registers (2 conflict-free ds_read_b32)
        const int* hpi = (const int*)hp;
        int hr0 = hpi[lane];         // k-pairs [0,64)
        int hr1 = hpi[64 + lane];    // k-pairs [64,128)

        float a0 = 0.f, a1 = 0.f;

        // k-pairs [0,64): VGPR weights, broadcast from hr0
#pragma unroll
        for (int kq = 0; kq < 16; ++kq) {
            DOTQ(4 * kq, hr0, wA[kq], wB[kq])
        }
        // k-pairs [64,96): VGPR weights, lanes 0..31 of hr1
#pragma unroll
        for (int kq = 16; kq < 24; ++kq) {
            DOTQ(4 * (kq - 16), hr1, wA[kq], wB[kq])
        }
        // k-pairs [96,128): LDS weights, lanes 32..63 of hr1
#pragma unroll
        for (int kq = 0; kq < 8; ++kq) {
            uint4 ta = Tl[kq * 1024 + t];
            uint4 tb = Tl[kq * 1024 + t + 512];
            DOTQ(32 + 4 * kq, hr1, ta, tb)
        }

        gates[t]       = a0 + xA;
        gates[t + 512] = a1 + xB;
        __syncthreads();
        if (t < 256) {
            int j = t;
            float gi = gates[j];
            float gf = gates[256 + j];
            float gg = gates[512 + j];
            float go = gates[768 + j];
            float ii = sigf(gi), ff = sigf(gf), g2 = tanhf_(gg), oo = sigf(go);
            cst = ff * cst + ii * g2;
            float h = oo * tanhf_(cst);
            float hx = __shfl_xor(h, 1);
            if (!(t & 1)) {
                uint32_t pk = packh2(h, hx);
                hp[j >> 1] = pk;
                outp[(size_t)row * 256 + d * 128 + (j >> 1)] = pk;
            }
        }
        __syncthreads();
    }
}

// ------------- emissions: em[8192 x 5] = x2p @ out_w + out_b -----------------
__global__ __launch_bounds__(256) void emis_kernel(
    const uint32_t* __restrict__ x2p, const float* __restrict__ ow,
    const float* __restrict__ ob, float* __restrict__ em)
{
    int i = blockIdx.x * blockDim.x + threadIdx.x;
    if (i >= NB * NS) return;
    const uint32_t* xr = x2p + (size_t)i * 256;
    float acc[NLAB];
#pragma unroll
    for (int l = 0; l < NLAB; ++l) acc[l] = ob[l];
    for (int p = 0; p < 256; ++p) {
        h2_t hv = __builtin_bit_cast(h2_t, xr[p]);
        float lo = (float)hv[0], hi = (float)hv[1];
        int k = 2 * p;
#pragma unroll
        for (int l = 0; l < NLAB; ++l)
            acc[l] += lo * ow[(size_t)k * NLAB + l] + hi * ow[(size_t)(k + 1) * NLAB + l];
    }
    float* e = em + (size_t)i * NLAB;
#pragma unroll
    for (int l = 0; l < NLAB; ++l) e[l] = acc[l];
}

// ------------- CRF: numerator + forward algorithm + mean ---------------------
__device__ __forceinline__ float lse5(const float* v) {
    float m = fmaxf(fmaxf(fmaxf(v[0], v[1]), fmaxf(v[2], v[3])), v[4]);
    float s = __expf(v[0] - m) + __expf(v[1] - m) + __expf(v[2] - m) +
              __expf(v[3] - m) + __expf(v[4] - m);
    return m + __logf(s);
}

__global__ __launch_bounds__(64) void crf_kernel(
    const float* __restrict__ em, const int* __restrict__ labels,
    const int* __restrict__ lengths, const float* __restrict__ cstart,
    const float* __restrict__ cend, const float* __restrict__ ctrans,
    float* __restrict__ outp)
{
    __shared__ float tr_s[25], st_s[5], en_s[5];
    int tid = threadIdx.x;
    if (tid < 25) tr_s[tid] = ctrans[tid];
    if (tid < 5)  { st_s[tid] = cstart[tid]; en_s[tid] = cend[tid]; }
    __syncthreads();

    int b = tid;
    int len = lengths[b];
    const int* tg = labels + (size_t)b * NS;
    const float* eb = em + (size_t)b * NS * NLAB;

    int prev = tg[0];
    float num = st_s[prev] + eb[prev];
    for (int t = 1; t < NS; ++t) {
        if (t < len) {
            int cur = tg[t];
            num += tr_s[prev * NLAB + cur] + eb[t * NLAB + cur];
            prev = cur;
        }
    }
    num += en_s[tg[len - 1]];

    float a[NLAB];
#pragma unroll
    for (int y = 0; y < NLAB; ++y) a[y] = st_s[y] + eb[y];
    for (int t = 1; t < NS; ++t) {
        if (t < len) {
            float na[NLAB];
#pragma unroll
            for (int y = 0; y < NLAB; ++y) {
                float v[NLAB];
#pragma unroll
                for (int x = 0; x < NLAB; ++x) v[x] = a[x] + tr_s[x * NLAB + y];
                na[y] = lse5(v) + eb[t * NLAB + y];
            }
#pragma unroll
            for (int y = 0; y < NLAB; ++y) a[y] = na[y];
        }
    }
    float v[NLAB];
#pragma unroll
    for (int y = 0; y < NLAB; ++y) v[y] = a[y] + en_s[y];
    float denom = lse5(v);

    float llh = num - denom;
#pragma unroll
    for (int off = 32; off > 0; off >>= 1) llh += __shfl_down(llh, off);
    if (tid == 0) outp[0] = -llh * (1.0f / 64.0f);
}

// ----------------------------- launcher --------------------------------------
extern "C" void kernel_launch(void* const* d_in, const int* in_sizes, int n_in,
                              void* d_out, int out_size, void* d_ws, size_t ws_size,
                              hipStream_t stream)
{
    const int*   word_ids = (const int*)d_in[0];
    const int*   char_ids = (const int*)d_in[1];
    const int*   labels   = (const int*)d_in[2];
    const int*   lengths  = (const int*)d_in[3];
    const float* word_emb = (const float*)d_in[4];
    const float* char_emb = (const float*)d_in[5];
    const float* cw3 = (const float*)d_in[6];
    const float* cb3 = (const float*)d_in[7];
    const float* cw4 = (const float*)d_in[8];
    const float* cb4 = (const float*)d_in[9];
    const float* cw5 = (const float*)d_in[10];
    const float* cb5 = (const float*)d_in[11];
    const float* out_w = (const float*)d_in[12];
    const float* out_b = (const float*)d_in[13];
    const float* crf_start = (const float*)d_in[14];
    const float* crf_end   = (const float*)d_in[15];
    const float* crf_trans = (const float*)d_in[16];
    const float* Wih_l0f = (const float*)d_in[17];
    const float* Whh_l0f = (const float*)d_in[18];
    const float* b_l0f   = (const float*)d_in[19];
    const float* Wih_l0r = (const float*)d_in[20];
    const float* Whh_l0r = (const float*)d_in[21];
    const float* b_l0r   = (const float*)d_in[22];
    const float* Wih_l1f = (const float*)d_in[23];
    const float* Whh_l1f = (const float*)d_in[24];
    const float* b_l1f   = (const float*)d_in[25];
    const float* Wih_l1r = (const float*)d_in[26];
    const float* Whh_l1r = (const float*)d_in[27];
    const float* b_l1r   = (const float*)d_in[28];

    // workspace layout (4-byte units), total 24,365,056 = 97.5 MB
    uint32_t* wsu = (uint32_t*)d_ws;
    uint32_t* x0p  = wsu;                         // 8192*225  = 1,843,200
    float*    xg_f = (float*)(wsu + 1843200);     // 8192*1024 = 8,388,608
    float*    xg_r = xg_f + 8388608;
    uint32_t* x1p  = (uint32_t*)(xg_r + 8388608); // 8192*256  = 2,097,152
    uint32_t* x2p  = x1p + 2097152;               // 2,097,152
    float*    em   = (float*)(x2p + 2097152);     // 40,960
    uint32_t* wp0f = (uint32_t*)(em + 40960);     // 225*1024  = 230,400
    uint32_t* wp0r = wp0f + 230400;
    uint32_t* wp1f = wp0r + 230400;               // 256*1024  = 262,144
    uint32_t* wp1r = wp1f + 262144;
    uint32_t* wh0f = wp1r + 262144;               // 131,072 each
    uint32_t* wh0r = wh0f + 131072;
    uint32_t* wh1f = wh0r + 131072;
    uint32_t* wh1r = wh1f + 131072;

    cnn_embed<<<2048, 256, 0, stream>>>(word_ids, char_ids, word_emb, char_emb,
                                        cw3, cb3, cw4, cb4, cw5, cb5, x0p);

    pack_wih<<<900, 256, 0, stream>>>(Wih_l0f, COMB, wp0f);
    pack_wih<<<900, 256, 0, stream>>>(Wih_l0r, COMB, wp0r);
    pack_wih<<<1024, 256, 0, stream>>>(Wih_l1f, 512, wp1f);
    pack_wih<<<1024, 256, 0, stream>>>(Wih_l1r, 512, wp1r);
    pack_whh<<<512, 256, 0, stream>>>(Whh_l0f, wh0f);
    pack_whh<<<512, 256, 0, stream>>>(Whh_l0r, wh0r);
    pack_whh<<<512, 256, 0, stream>>>(Whh_l1f, wh1f);
    pack_whh<<<512, 256, 0, stream>>>(Whh_l1r, wh1r);

    dim3 gGemm(64, 16);
    gemm_f16<<<gGemm, 256, 0, stream>>>(x0p, 225, wp0f, wp0r, b_l0f, b_l0r, xg_f, xg_r);
    lstm_rec6<<<128, 512, 0, stream>>>(xg_f, xg_r, wh0f, wh0r, x1p);

    gemm_f16<<<gGemm, 256, 0, stream>>>(x1p, 256, wp1f, wp1r, b_l1f, b_l1r, xg_f, xg_r);
    lstm_rec6<<<128, 512, 0, stream>>>(xg_f, xg_r, wh1f, wh1r, x2p);

    emis_kernel<<<32, 256, 0, stream>>>(x2p, out_w, out_b, em);
    crf_kernel<<<1, 64, 0, stream>>>(em, labels, lengths, crf_start, crf_end, crf_trans,
                                     (float*)d_out);
}

// Round 7
// 1182.928 us; speedup vs baseline: 1.5928x; 1.0012x over previous
//
#include <hip/hip_runtime.h>
#include <hip/hip_fp16.h>
#include <math.h>
#include <stdint.h>

// Problem constants
#define NB   64      // batch
#define NS   128     // seq len
#define NW   16      // word length (chars)
#define CD   50      // char emb dim
#define NF_  50      // filters per kernel size
#define WD   300     // word emb dim
#define COMB 450     // WD + 3*NF  (even -> 225 f16 pairs)
#define HID  256
#define G4   1024    // 4*HID
#define NLAB 5

typedef _Float16 h2_t __attribute__((ext_vector_type(2)));

__device__ __forceinline__ float sigf(float x)   { return 1.0f / (1.0f + __expf(-x)); }
__device__ __forceinline__ float tanhf_(float x) { return 1.0f - 2.0f / (__expf(2.0f * x) + 1.0f); }

__device__ __forceinline__ float dot2f(uint32_t a, uint32_t b, float c) {
#if __has_builtin(__builtin_amdgcn_fdot2)
    return __builtin_amdgcn_fdot2(__builtin_bit_cast(h2_t, a),
                                  __builtin_bit_cast(h2_t, b), c, false);
#else
    h2_t ah = __builtin_bit_cast(h2_t, a), bh = __builtin_bit_cast(h2_t, b);
    return c + (float)ah[0] * (float)bh[0] + (float)ah[1] * (float)bh[1];
#endif
}

__device__ __forceinline__ uint32_t packh2(float lo, float hi) {
    __half l = __float2half(lo), h = __float2half(hi);
    return ((uint32_t)__half_as_ushort(h) << 16) | (uint32_t)__half_as_ushort(l);
}

// ---------------- CNN + embedding concat -> x0p (8192 x 225 u32, f16 pairs) --
__global__ __launch_bounds__(256) void cnn_embed(
    const int* __restrict__ word_ids, const int* __restrict__ char_ids,
    const float* __restrict__ word_emb, const float* __restrict__ char_emb,
    const float* __restrict__ w3, const float* __restrict__ b3,
    const float* __restrict__ w4, const float* __restrict__ b4,
    const float* __restrict__ w5, const float* __restrict__ b5,
    uint32_t* __restrict__ x0p)
{
    __shared__ float ce[4][NW][CD];
    __shared__ float cv[4][152];            // conv outputs per position
    int tid  = threadIdx.x;
    int g    = tid >> 6;
    int lane = tid & 63;
    int pos  = blockIdx.x * 4 + g;          // 0..8191

    const int* cid = char_ids + (size_t)pos * NW;
    for (int idx = lane; idx < NW * CD; idx += 64) {
        int w  = idx / CD;
        int cc = idx - w * CD;
        ce[g][w][cc] = char_emb[(size_t)cid[w] * CD + cc];
    }
    // word embedding -> packed pairs 0..149
    {
        int wid = word_ids[pos];
        const float* src = word_emb + (size_t)wid * WD;
        uint32_t* dst = x0p + (size_t)pos * 225;
        for (int idx = lane; idx < 150; idx += 64) {
            float2 v = *(const float2*)(src + 2 * idx);
            dst[idx] = packh2(v.x, v.y);
        }
    }
    __syncthreads();

    int f = lane;
    if (f < NF_) {
        float a3[16], a4[17], a5[16];
        float bb3 = b3[f], bb4 = b4[f], bb5 = b5[f];
#pragma unroll
        for (int p = 0; p < 16; ++p) { a3[p] = bb3; a5[p] = bb5; }
#pragma unroll
        for (int p = 0; p < 17; ++p) a4[p] = bb4;

        for (int c = 0; c < CD; ++c) {
            float w3r[3], w4r[4], w5r[5];
#pragma unroll
            for (int t = 0; t < 3; ++t) w3r[t] = w3[(t * CD + c) * NF_ + f];
#pragma unroll
            for (int t = 0; t < 4; ++t) w4r[t] = w4[(t * CD + c) * NF_ + f];
#pragma unroll
            for (int t = 0; t < 5; ++t) w5r[t] = w5[(t * CD + c) * NF_ + f];
#pragma unroll
            for (int ip = 0; ip < 16; ++ip) {
                float v = ce[g][ip][c];
#pragma unroll
                for (int t = 0; t < 3; ++t) { int p = ip + 1 - t; if (p >= 0 && p < 16) a3[p] += v * w3r[t]; }
#pragma unroll
                for (int t = 0; t < 4; ++t) { int p = ip + 2 - t; if (p >= 0 && p < 17) a4[p] += v * w4r[t]; }
#pragma unroll
                for (int t = 0; t < 5; ++t) { int p = ip + 2 - t; if (p >= 0 && p < 16) a5[p] += v * w5r[t]; }
            }
        }
        float m3 = 0.f, m4 = 0.f, m5 = 0.f;
#pragma unroll
        for (int p = 0; p < 16; ++p) m3 = fmaxf(m3, a3[p]);
#pragma unroll
        for (int p = 0; p < 17; ++p) m4 = fmaxf(m4, a4[p]);
#pragma unroll
        for (int p = 0; p < 16; ++p) m5 = fmaxf(m5, a5[p]);
        cv[g][f] = m3; cv[g][50 + f] = m4; cv[g][100 + f] = m5;
    }
    __syncthreads();
    // pack conv pairs 150..224
    {
        uint32_t* dst = x0p + (size_t)pos * 225 + 150;
        for (int idx = lane; idx < 75; idx += 64)
            dst[idx] = packh2(cv[g][2 * idx], cv[g][2 * idx + 1]);
    }
}

// ------------- weight packs ---------------------------------------------------
// Wih: P[kp*1024 + n] = h2(W[2kp][n], W[2kp+1][n])
__global__ __launch_bounds__(256) void pack_wih(
    const float* __restrict__ W, int K, uint32_t* __restrict__ P)
{
    int idx = blockIdx.x * 256 + threadIdx.x;
    int K2 = K >> 1;
    if (idx >= K2 * 1024) return;
    int n = idx & 1023, kp = idx >> 10;
    int k0 = 2 * kp;
    float lo = W[(size_t)k0 * 1024 + n];
    float hi = W[(size_t)(k0 + 1) * 1024 + n];
    P[idx] = packh2(lo, hi);
}

// Whh: P[(kq*1024+col)*4+kk] = h2(W[8kq+2kk][col], W[8kq+2kk+1][col])
__global__ __launch_bounds__(256) void pack_whh(
    const float* __restrict__ W, uint32_t* __restrict__ P)
{
    int idx = blockIdx.x * 256 + threadIdx.x;     // 32*1024*4 = 131072
    if (idx >= 131072) return;
    int kk = idx & 3, col = (idx >> 2) & 1023, kq = idx >> 12;
    int k = kq * 8 + kk * 2;
    float lo = W[(size_t)k * G4 + col];
    float hi = W[(size_t)(k + 1) * G4 + col];
    P[idx] = packh2(lo, hi);
}

// ------------- xg GEMM (f16 dot2): C[8192 x 1024] = Ap @ Wp + bias -----------
__global__ __launch_bounds__(256) void gemm_f16(
    const uint32_t* __restrict__ Ap, int K2,
    const uint32_t* __restrict__ Wpf, const uint32_t* __restrict__ Wpr,
    const float* __restrict__ bf, const float* __restrict__ br,
    float* __restrict__ Cf, float* __restrict__ Cr)
{
    int by  = blockIdx.y;
    int dir = by >> 3;
    int n0  = (by & 7) * 128;
    int m0  = blockIdx.x * 128;
    const uint32_t* Wp = dir ? Wpr : Wpf;
    const float* bias  = dir ? br : bf;
    float* C           = dir ? Cr : Cf;

    __shared__ uint32_t As[8][132];
    __shared__ uint32_t Bs[8][132];

    int tid = threadIdx.x;
    int ka = tid & 7,  ma = tid >> 3;       // A: 8 kp x 32 rows (x4)
    int kb = tid >> 7, nb = tid & 127;      // B: 2 kp (x4) x 128 n
    int tx = tid & 15, ty = tid >> 4;
    int row0 = ty * 8, col0 = tx * 8;

    float acc[8][8] = {};

    for (int kp0 = 0; kp0 < K2; kp0 += 8) {
#pragma unroll
        for (int i = 0; i < 4; ++i) {
            uint32_t v = 0;
            if (kp0 + ka < K2) v = Ap[(size_t)(m0 + ma + 32 * i) * K2 + kp0 + ka];
            As[ka][ma + 32 * i] = v;
        }
#pragma unroll
        for (int i = 0; i < 4; ++i) {
            int kp = kb + 2 * i;
            uint32_t v = 0;
            if (kp0 + kp < K2) v = Wp[(size_t)(kp0 + kp) * G4 + n0 + nb];
            Bs[kp][nb] = v;
        }
        __syncthreads();
#pragma unroll
        for (int kp = 0; kp < 8; ++kp) {
            uint32_t a[8], b[8];
            *(uint4*)&a[0] = *(const uint4*)&As[kp][row0];
            *(uint4*)&a[4] = *(const uint4*)&As[kp][row0 + 4];
            *(uint4*)&b[0] = *(const uint4*)&Bs[kp][col0];
            *(uint4*)&b[4] = *(const uint4*)&Bs[kp][col0 + 4];
#pragma unroll
            for (int i = 0; i < 8; ++i)
#pragma unroll
                for (int j = 0; j < 8; ++j)
                    acc[i][j] = dot2f(a[i], b[j], acc[i][j]);
        }
        __syncthreads();
    }
#pragma unroll
    for (int i = 0; i < 8; ++i) {
        size_t crow = (size_t)(m0 + row0 + i) * G4 + n0 + col0;
#pragma unroll
        for (int j = 0; j < 8; j += 4) {
            float4 o;
            o.x = acc[i][j]     + bias[n0 + col0 + j];
            o.y = acc[i][j + 1] + bias[n0 + col0 + j + 1];
            o.z = acc[i][j + 2] + bias[n0 + col0 + j + 2];
            o.w = acc[i][j + 3] + bias[n0 + col0 + j + 3];
            *(float4*)&C[crow + j] = o;
        }
    }
}

// ------------- LSTM recurrence v7: 128 blocks x 512 thr -----------------------
// Block per (batch, dir). Thread owns cols {t, t+512} for ONE batch row.
// Whh residency: k-pairs [0,96) VGPR-resident (192 regs), [96,128) LDS (128KB).
// KEY FIX vs rec6: __launch_bounds__(512, 1). The previous (512,2) capped the
// allocator at 128 VGPRs (VGPR_Count=116 in rocprof) and force-spilled the
// weight tier to scratch -> per-step L2 re-reads. Grid is 128 blocks on 256
// CUs, so min-2-blocks/CU bought nothing. With 256-VGPR budget the volatile
// tier stays truly register-resident: zero per-step weight memory traffic.
#define DOT1(LANE, HREG, WA, WB) { \
    uint32_t h_ = (uint32_t)__builtin_amdgcn_readlane((HREG), (LANE)); \
    a0 = dot2f(h_, (WA), a0); a1 = dot2f(h_, (WB), a1); }

#define DOTQ(LB, HREG, WQA, WQB) \
    DOT1((LB) + 0, HREG, (WQA).x, (WQB).x) \
    DOT1((LB) + 1, HREG, (WQA).y, (WQB).y) \
    DOT1((LB) + 2, HREG, (WQA).z, (WQB).z) \
    DOT1((LB) + 3, HREG, (WQA).w, (WQB).w)

__global__ __launch_bounds__(512, 1) void lstm_rec7(
    const float* __restrict__ xg_f, const float* __restrict__ xg_r,
    const uint32_t* __restrict__ Pf, const uint32_t* __restrict__ Pr,
    uint32_t* __restrict__ outp)   // [8192][256] u32: row*256 + d*128 + jp
{
    int bid = blockIdx.x;           // 128 = 64 batches x 2 dirs
    int b = bid >> 1, d = bid & 1;
    const float* xg = d ? xg_r : xg_f;
    const uint4* P4 = (const uint4*)(d ? Pr : Pf);   // [kq*1024 + col]

    __shared__ alignas(16) uint32_t hp[128];    // packed f16 h pairs (1 row)
    __shared__ float gates[G4];
    __shared__ alignas(16) uint4 Tl[8 * 1024];  // kq 24..31, all cols (128 KB)

    int t = threadIdx.x;            // 0..511
    int lane = t & 63;

    // fill LDS weight tier (once)
    for (int i = t; i < 8192; i += 512) Tl[i] = P4[24 * 1024 + i];
    if (t < 128) hp[t] = 0;
    float cst = 0.f;                // cell state for j=t (threads 0..255)

    // VGPR tier: kq 0..23 (k-pairs 0..95), cols t and t+512.
    // volatile: forces the values to stay in registers (non-rematerializable).
    volatile const uint4* P4v = P4;
    uint4 wA[24], wB[24];
#pragma unroll
    for (int kq = 0; kq < 24; ++kq) {
        uint4 va, vb;
        va.x = P4v[kq * 1024 + t].x;        va.y = P4v[kq * 1024 + t].y;
        va.z = P4v[kq * 1024 + t].z;        va.w = P4v[kq * 1024 + t].w;
        vb.x = P4v[kq * 1024 + t + 512].x;  vb.y = P4v[kq * 1024 + t + 512].y;
        vb.z = P4v[kq * 1024 + t + 512].z;  vb.w = P4v[kq * 1024 + t + 512].w;
        wA[kq] = va; wB[kq] = vb;
    }
    __syncthreads();

    for (int s = 0; s < NS; ++s) {
        int te = d ? (NS - 1 - s) : s;
        int row = b * NS + te;
        size_t r0 = (size_t)row * G4;
        float xA = xg[r0 + t];       // issued early, used after dot loop
        float xB = xg[r0 + 512 + t];

        // h into per-wave registers (2 conflict-free ds_read_b32)
        const int* hpi = (const int*)hp;
        int hr0 = hpi[lane];         // k-pairs [0,64)
        int hr1 = hpi[64 + lane];    // k-pairs [64,128)

        float a0 = 0.f, a1 = 0.f;

        // k-pairs [0,64): VGPR weights, broadcast from hr0
#pragma unroll
        for (int kq = 0; kq < 16; ++kq) {
            DOTQ(4 * kq, hr0, wA[kq], wB[kq])
        }
        // k-pairs [64,96): VGPR weights, lanes 0..31 of hr1
#pragma unroll
        for (int kq = 16; kq < 24; ++kq) {
            DOTQ(4 * (kq - 16), hr1, wA[kq], wB[kq])
        }
        // k-pairs [96,128): LDS weights, lanes 32..63 of hr1
#pragma unroll
        for (int kq = 0; kq < 8; ++kq) {
            uint4 ta = Tl[kq * 1024 + t];
            uint4 tb = Tl[kq * 1024 + t + 512];
            DOTQ(32 + 4 * kq, hr1, ta, tb)
        }

        gates[t]       = a0 + xA;
        gates[t + 512] = a1 + xB;
        __syncthreads();
        if (t < 256) {
            int j = t;
            float gi = gates[j];
            float gf = gates[256 + j];
            float gg = gates[512 + j];
            float go = gates[768 + j];
            float ii = sigf(gi), ff = sigf(gf), g2 = tanhf_(gg), oo = sigf(go);
            cst = ff * cst + ii * g2;
            float h = oo * tanhf_(cst);
            float hx = __shfl_xor(h, 1);
            if (!(t & 1)) {
                uint32_t pk = packh2(h, hx);
                hp[j >> 1] = pk;
                outp[(size_t)row * 256 + d * 128 + (j >> 1)] = pk;
            }
        }
        __syncthreads();
    }
}

// ------------- emissions: em[8192 x 5] = x2p @ out_w + out_b -----------------
__global__ __launch_bounds__(256) void emis_kernel(
    const uint32_t* __restrict__ x2p, const float* __restrict__ ow,
    const float* __restrict__ ob, float* __restrict__ em)
{
    int i = blockIdx.x * blockDim.x + threadIdx.x;
    if (i >= NB * NS) return;
    const uint32_t* xr = x2p + (size_t)i * 256;
    float acc[NLAB];
#pragma unroll
    for (int l = 0; l < NLAB; ++l) acc[l] = ob[l];
    for (int p = 0; p < 256; ++p) {
        h2_t hv = __builtin_bit_cast(h2_t, xr[p]);
        float lo = (float)hv[0], hi = (float)hv[1];
        int k = 2 * p;
#pragma unroll
        for (int l = 0; l < NLAB; ++l)
            acc[l] += lo * ow[(size_t)k * NLAB + l] + hi * ow[(size_t)(k + 1) * NLAB + l];
    }
    float* e = em + (size_t)i * NLAB;
#pragma unroll
    for (int l = 0; l < NLAB; ++l) e[l] = acc[l];
}

// ------------- CRF: numerator + forward algorithm + mean ---------------------
__device__ __forceinline__ float lse5(const float* v) {
    float m = fmaxf(fmaxf(fmaxf(v[0], v[1]), fmaxf(v[2], v[3])), v[4]);
    float s = __expf(v[0] - m) + __expf(v[1] - m) + __expf(v[2] - m) +
              __expf(v[3] - m) + __expf(v[4] - m);
    return m + __logf(s);
}

__global__ __launch_bounds__(64) void crf_kernel(
    const float* __restrict__ em, const int* __restrict__ labels,
    const int* __restrict__ lengths, const float* __restrict__ cstart,
    const float* __restrict__ cend, const float* __restrict__ ctrans,
    float* __restrict__ outp)
{
    __shared__ float tr_s[25], st_s[5], en_s[5];
    int tid = threadIdx.x;
    if (tid < 25) tr_s[tid] = ctrans[tid];
    if (tid < 5)  { st_s[tid] = cstart[tid]; en_s[tid] = cend[tid]; }
    __syncthreads();

    int b = tid;
    int len = lengths[b];
    const int* tg = labels + (size_t)b * NS;
    const float* eb = em + (size_t)b * NS * NLAB;

    int prev = tg[0];
    float num = st_s[prev] + eb[prev];
    for (int t = 1; t < NS; ++t) {
        if (t < len) {
            int cur = tg[t];
            num += tr_s[prev * NLAB + cur] + eb[t * NLAB + cur];
            prev = cur;
        }
    }
    num += en_s[tg[len - 1]];

    float a[NLAB];
#pragma unroll
    for (int y = 0; y < NLAB; ++y) a[y] = st_s[y] + eb[y];
    for (int t = 1; t < NS; ++t) {
        if (t < len) {
            float na[NLAB];
#pragma unroll
            for (int y = 0; y < NLAB; ++y) {
                float v[NLAB];
#pragma unroll
                for (int x = 0; x < NLAB; ++x) v[x] = a[x] + tr_s[x * NLAB + y];
                na[y] = lse5(v) + eb[t * NLAB + y];
            }
#pragma unroll
            for (int y = 0; y < NLAB; ++y) a[y] = na[y];
        }
    }
    float v[NLAB];
#pragma unroll
    for (int y = 0; y < NLAB; ++y) v[y] = a[y] + en_s[y];
    float denom = lse5(v);

    float llh = num - denom;
#pragma unroll
    for (int off = 32; off > 0; off >>= 1) llh += __shfl_down(llh, off);
    if (tid == 0) outp[0] = -llh * (1.0f / 64.0f);
}

// ----------------------------- launcher --------------------------------------
extern "C" void kernel_launch(void* const* d_in, const int* in_sizes, int n_in,
                              void* d_out, int out_size, void* d_ws, size_t ws_size,
                              hipStream_t stream)
{
    const int*   word_ids = (const int*)d_in[0];
    const int*   char_ids = (const int*)d_in[1];
    const int*   labels   = (const int*)d_in[2];
    const int*   lengths  = (const int*)d_in[3];
    const float* word_emb = (const float*)d_in[4];
    const float* char_emb = (const float*)d_in[5];
    const float* cw3 = (const float*)d_in[6];
    const float* cb3 = (const float*)d_in[7];
    const float* cw4 = (const float*)d_in[8];
    const float* cb4 = (const float*)d_in[9];
    const float* cw5 = (const float*)d_in[10];
    const float* cb5 = (const float*)d_in[11];
    const float* out_w = (const float*)d_in[12];
    const float* out_b = (const float*)d_in[13];
    const float* crf_start = (const float*)d_in[14];
    const float* crf_end   = (const float*)d_in[15];
    const float* crf_trans = (const float*)d_in[16];
    const float* Wih_l0f = (const float*)d_in[17];
    const float* Whh_l0f = (const float*)d_in[18];
    const float* b_l0f   = (const float*)d_in[19];
    const float* Wih_l0r = (const float*)d_in[20];
    const float* Whh_l0r = (const float*)d_in[21];
    const float* b_l0r   = (const float*)d_in[22];
    const float* Wih_l1f = (const float*)d_in[23];
    const float* Whh_l1f = (const float*)d_in[24];
    const float* b_l1f   = (const float*)d_in[25];
    const float* Wih_l1r = (const float*)d_in[26];
    const float* Whh_l1r = (const float*)d_in[27];
    const float* b_l1r   = (const float*)d_in[28];

    // workspace layout (4-byte units), total 24,365,056 = 97.5 MB
    uint32_t* wsu = (uint32_t*)d_ws;
    uint32_t* x0p  = wsu;                         // 8192*225  = 1,843,200
    float*    xg_f = (float*)(wsu + 1843200);     // 8192*1024 = 8,388,608
    float*    xg_r = xg_f + 8388608;
    uint32_t* x1p  = (uint32_t*)(xg_r + 8388608); // 8192*256  = 2,097,152
    uint32_t* x2p  = x1p + 2097152;               // 2,097,152
    float*    em   = (float*)(x2p + 2097152);     // 40,960
    uint32_t* wp0f = (uint32_t*)(em + 40960);     // 225*1024  = 230,400
    uint32_t* wp0r = wp0f + 230400;
    uint32_t* wp1f = wp0r + 230400;               // 256*1024  = 262,144
    uint32_t* wp1r = wp1f + 262144;
    uint32_t* wh0f = wp1r + 262144;               // 131,072 each
    uint32_t* wh0r = wh0f + 131072;
    uint32_t* wh1f = wh0r + 131072;
    uint32_t* wh1r = wh1f + 131072;

    cnn_embed<<<2048, 256, 0, stream>>>(word_ids, char_ids, word_emb, char_emb,
                                        cw3, cb3, cw4, cb4, cw5, cb5, x0p);

    pack_wih<<<900, 256, 0, stream>>>(Wih_l0f, COMB, wp0f);
    pack_wih<<<900, 256, 0, stream>>>(Wih_l0r, COMB, wp0r);
    pack_wih<<<1024, 256, 0, stream>>>(Wih_l1f, 512, wp1f);
    pack_wih<<<1024, 256, 0, stream>>>(Wih_l1r, 512, wp1r);
    pack_whh<<<512, 256, 0, stream>>>(Whh_l0f, wh0f);
    pack_whh<<<512, 256, 0, stream>>>(Whh_l0r, wh0r);
    pack_whh<<<512, 256, 0, stream>>>(Whh_l1f, wh1f);
    pack_whh<<<512, 256, 0, stream>>>(Whh_l1r, wh1r);

    dim3 gGemm(64, 16);
    gemm_f16<<<gGemm, 256, 0, stream>>>(x0p, 225, wp0f, wp0r, b_l0f, b_l0r, xg_f, xg_r);
    lstm_rec7<<<128, 512, 0, stream>>>(xg_f, xg_r, wh0f, wh0r, x1p);

    gemm_f16<<<gGemm, 256, 0, stream>>>(x1p, 256, wp1f, wp1r, b_l1f, b_l1r, xg_f, xg_r);
    lstm_rec7<<<128, 512, 0, stream>>>(xg_f, xg_r, wh1f, wh1r, x2p);

    emis_kernel<<<32, 256, 0, stream>>>(x2p, out_w, out_b, em);
    crf_kernel<<<1, 64, 0, stream>>>(em, labels, lengths, crf_start, crf_end, crf_trans,
                                     (float*)d_out);
}